// Round 7
// baseline (1156.616 us; speedup 1.0000x reference)
//
#include <hip/hip_runtime.h>
#include <hip/hip_bf16.h>
#include <math.h>

#define NN 20000
#define EE 640000
#define HH 128
#define LL 12
#define DOUT_ 16
#define EPS_ 1e-7f
#define LN_EPS_ 1e-5f

typedef unsigned short u16;
typedef unsigned int u32;
typedef __attribute__((ext_vector_type(8))) short bf16x8;
typedef __attribute__((ext_vector_type(4))) float f32x4;

__device__ inline u16 bf16_rne(float v) {
  u32 u = __float_as_uint(v);
  return (u16)((u + 0x7FFFu + ((u >> 16) & 1u)) >> 16);
}
__device__ inline float bf16_tof(u16 h) { return __uint_as_float(((u32)h) << 16); }

// ---------------- CSR build ----------------
__global__ __launch_bounds__(256) void hist_kernel(const int* __restrict__ dst, int* __restrict__ deg) {
  int e = blockIdx.x * 256 + threadIdx.x;
  if (e < EE) atomicAdd(&deg[dst[e]], 1);
}

__global__ __launch_bounds__(1024) void scan_kernel(const int* __restrict__ deg, int* __restrict__ off,
                                                    int* __restrict__ cur) {
  __shared__ int part[1024];
  int tid = threadIdx.x;
  const int CH = (NN + 1023) >> 10;   // 20
  int base = tid * CH;
  int s = 0;
  for (int j = 0; j < CH; ++j) { int i = base + j; if (i < NN) s += deg[i]; }
  part[tid] = s;
  __syncthreads();
  for (int d = 1; d < 1024; d <<= 1) {
    int v = (tid >= d) ? part[tid - d] : 0;
    __syncthreads();
    part[tid] += v;
    __syncthreads();
  }
  int run = part[tid] - s;  // exclusive prefix
  for (int j = 0; j < CH; ++j) {
    int i = base + j;
    if (i < NN) { off[i] = run; cur[i] = run; run += deg[i]; }
  }
  if (tid == 1023) off[NN] = part[1023];
}

// interleaved edge record: edata[2p] = {src_bits,_,_,_}, edata[2p+1] = edge_attr
__global__ __launch_bounds__(256) void scatter_kernel(const int* __restrict__ src, const int* __restrict__ dst,
                                                      const float4* __restrict__ ea, int* __restrict__ cur,
                                                      float4* __restrict__ edata) {
  int e = blockIdx.x * 256 + threadIdx.x;
  if (e >= EE) return;
  int d = dst[e];
  int p = atomicAdd(&cur[d], 1);
  edata[(size_t)2*p]     = make_float4(__int_as_float(src[e]), 0.f, 0.f, 0.f);
  edata[(size_t)2*p + 1] = ea[e];
}

// ---------------- weight pack: fp32 [L][K][N] -> bf16 hi/lo MFMA-fragment order ----------------
__global__ __launch_bounds__(256) void wpack_kernel(const float* __restrict__ w, u16* __restrict__ dh,
                                                    u16* __restrict__ dl, int K, int N, int KSC) {
  int fid = blockIdx.x * 256 + threadIdx.x;
  int perL = (K * N) >> 3;
  if (fid >= LL * perL) return;
  int l = fid / perL, r = fid % perL;
  int lane = r & 63;
  int r2 = r >> 6;
  int ks2 = r2 % KSC; r2 /= KSC;
  int NT = N >> 4;
  int tI = r2 % NT;
  int chunk = r2 / NT;
  int c16 = lane & 15, kg = lane >> 4;
  int n = tI * 16 + c16;
  int k0 = (chunk * KSC + ks2) * 32 + kg * 8;
  const float* ws = w + (size_t)l * K * N;
  u16* oh = dh + (size_t)fid * 8;
  u16* ol = dl + (size_t)fid * 8;
  #pragma unroll
  for (int j = 0; j < 8; ++j) {
    float v = ws[(size_t)(k0 + j) * N + n];
    u16 hi = bf16_rne(v);
    oh[j] = hi;
    ol[j] = bf16_rne(v - bf16_tof(hi));
  }
}

// ---------------- encoder: h fp32 + hb bf16 plane ----------------
__global__ __launch_bounds__(256) void encoder_kernel(const float* __restrict__ x, const float* __restrict__ w,
                                                      const float* __restrict__ b, float* __restrict__ h,
                                                      u16* __restrict__ hb) {
  int id = blockIdx.x * 256 + threadIdx.x;
  if (id >= NN * 64) return;
  int n = id >> 6, cp = id & 63;
  int c0 = cp * 2;
  float x0 = x[n*3+0], x1 = x[n*3+1], x2 = x[n*3+2];
  float vx = b[c0]   + x0*w[c0]   + x1*w[HH+c0]   + x2*w[2*HH+c0];
  float vy = b[c0+1] + x0*w[c0+1] + x1*w[HH+c0+1] + x2*w[2*HH+c0+1];
  *(float2*)&h[(size_t)n*HH + c0] = make_float2(vx, vy);
  *(u32*)&hb[(size_t)n*HH + c0] = (u32)bf16_rne(vx) | ((u32)bf16_rne(vy) << 16);
}

// ---------------- GENConv aggregation: wave per dst node, scalarized edge records ----------------
// Loop bounds forced to SGPR via readfirstlane -> edge indices, record addresses
// and record values (src idx + edge attr) become scalar (s_load/SALU), leaving
// VALU only the per-channel math. Direct-exp softmax via exp2 (log2e folded).
__global__ __launch_bounds__(256) void conv_kernel(const float* __restrict__ hn,
                                                   const u16* __restrict__ hb,
                                                   const int* __restrict__ off,
                                                   const float4* __restrict__ edata,
                                                   const float* __restrict__ eew, const float* __restrict__ eeb,
                                                   const float* __restrict__ t, int layer,
                                                   u16* __restrict__ tmpH, u16* __restrict__ tmpL) {
  int wid = blockIdx.x * 4 + (threadIdx.x >> 6);
  int lane = threadIdx.x & 63;
  if (wid >= NN) return;
  int c0 = lane * 2;
  float ti = t[layer];
  float tl = ti * 1.44269504089f;   // p = exp2(m * tl) == exp(m * ti)
  float w0x = eew[c0],      w0y = eew[c0+1];
  float w1x = eew[HH+c0],   w1y = eew[HH+c0+1];
  float w2x = eew[2*HH+c0], w2y = eew[2*HH+c0+1];
  float w3x = eew[3*HH+c0], w3y = eew[3*HH+c0+1];
  float bx = eeb[c0], by = eeb[c0+1];
  int e0 = __builtin_amdgcn_readfirstlane(off[wid]);
  int e1 = __builtin_amdgcn_readfirstlane(off[wid + 1]);
  float2 hd = *(const float2*)&hn[(size_t)wid*HH + c0];
  float den0 = 0.f, den1 = 0.f, num0 = 0.f, num1 = 0.f;
  const int* edi = (const int*)edata;

  const int UF = 8;
  for (int e = e0; e < e1; e += UF) {
    int si[UF]; float4 av[UF]; float okf[UF];
    #pragma unroll
    for (int u = 0; u < UF; ++u) {
      int ee = e + u;
      int idx = (ee < e1) ? ee : (e1 - 1);   // scalar clamp
      si[u] = edi[(size_t)8 * idx];           // scalar load (uniform addr)
      av[u] = edata[(size_t)2 * idx + 1];     // scalar load x4
      okf[u] = (ee < e1) ? 1.f : 0.f;         // scalar predicate
    }
    u32 hv[UF];
    #pragma unroll
    for (int u = 0; u < UF; ++u) hv[u] = *(const u32*)&hb[((u32)si[u] << 7) + c0];
    #pragma unroll
    for (int u = 0; u < UF; ++u) {
      float hx = bf16_tof((u16)(hv[u] & 0xffffu));
      float hy = bf16_tof((u16)(hv[u] >> 16));
      float eax = fmaf(av[u].w, w3x, fmaf(av[u].z, w2x, fmaf(av[u].y, w1x, fmaf(av[u].x, w0x, bx))));
      float eay = fmaf(av[u].w, w3y, fmaf(av[u].z, w2y, fmaf(av[u].y, w1y, fmaf(av[u].x, w0y, by))));
      float m0 = fmaxf(hx + eax, 0.f) + EPS_;
      float m1 = fmaxf(hy + eay, 0.f) + EPS_;
      float p0 = exp2f(m0 * tl) * okf[u];
      float p1 = exp2f(m1 * tl) * okf[u];
      den0 += p0; den1 += p1;
      num0 = fmaf(m0, p0, num0);
      num1 = fmaf(m1, p1, num1);
    }
  }
  float v0 = num0 / (den0 + 1e-16f) + hd.x;
  float v1 = num1 / (den1 + 1e-16f) + hd.y;
  u16 h0 = bf16_rne(v0), h1 = bf16_rne(v1);
  u16 l0 = bf16_rne(v0 - bf16_tof(h0)), l1 = bf16_rne(v1 - bf16_tof(h1));
  *(u32*)&tmpH[(size_t)wid*HH + c0] = (u32)h0 | ((u32)h1 << 16);
  *(u32*)&tmpL[(size_t)wid*HH + c0] = (u32)l0 | ((u32)l1 << 16);
}

// ---------------- GEMM1 (20000x128 @ 128x256) 3xBF16 MFMA, LDS-staged packed B ----------------
__global__ __launch_bounds__(256) void gemm1_mfma(const u16* __restrict__ Ah, const u16* __restrict__ Al,
                                                  const u16* __restrict__ Bh, const u16* __restrict__ Bl,
                                                  const float* __restrict__ bias,
                                                  const float* __restrict__ g, const float* __restrict__ bb,
                                                  u16* __restrict__ Uh, u16* __restrict__ Ul) {
  __shared__ u16 Bs[2][16384];
  int tid = threadIdx.x;
  int wv = tid >> 6, lane = tid & 63;
  int c16 = lane & 15, kg = lane >> 4;
  int row0 = blockIdx.x * 64 + wv * 16;
  int arow = row0 + c16; if (arow > NN - 1) arow = NN - 1;
  const u16* pAh = Ah + (size_t)arow * HH + kg * 8;
  const u16* pAl = Al + (size_t)arow * HH + kg * 8;
  f32x4 acc[16];
  #pragma unroll
  for (int tI = 0; tI < 16; ++tI) acc[tI] = (f32x4){0.f, 0.f, 0.f, 0.f};

  #pragma unroll
  for (int chunk = 0; chunk < 2; ++chunk) {
    const u16* sh = Bh + chunk * 16384;
    const u16* sl = Bl + chunk * 16384;
    #pragma unroll
    for (int it = 0; it < 8; ++it) {
      int idx = (it * 256 + tid) * 8;
      *(f32x4*)&Bs[0][idx] = *(const f32x4*)&sh[idx];
      *(f32x4*)&Bs[1][idx] = *(const f32x4*)&sl[idx];
    }
    __syncthreads();
    #pragma unroll
    for (int ks2 = 0; ks2 < 2; ++ks2) {
      int ks = chunk * 2 + ks2;
      bf16x8 ah = *(const bf16x8*)(pAh + ks * 32);
      bf16x8 al = *(const bf16x8*)(pAl + ks * 32);
      #pragma unroll
      for (int tI = 0; tI < 16; ++tI) {
        int boff = ((tI * 2 + ks2) * 64 + lane) * 8;
        bf16x8 bh = *(const bf16x8*)&Bs[0][boff];
        bf16x8 bl = *(const bf16x8*)&Bs[1][boff];
        acc[tI] = __builtin_amdgcn_mfma_f32_16x16x32_bf16(ah, bh, acc[tI], 0, 0, 0);
        acc[tI] = __builtin_amdgcn_mfma_f32_16x16x32_bf16(al, bh, acc[tI], 0, 0, 0);
        acc[tI] = __builtin_amdgcn_mfma_f32_16x16x32_bf16(ah, bl, acc[tI], 0, 0, 0);
      }
    }
    __syncthreads();
  }

  float bv[16], gv[16], bbv[16];
  #pragma unroll
  for (int tI = 0; tI < 16; ++tI) {
    int c = tI * 16 + c16;
    bv[tI] = bias[c]; gv[tI] = g[c]; bbv[tI] = bb[c];
  }
  #pragma unroll
  for (int j = 0; j < 4; ++j) {
    int row = row0 + kg * 4 + j;
    float xv[16], s = 0.f;
    #pragma unroll
    for (int tI = 0; tI < 16; ++tI) { xv[tI] = acc[tI][j] + bv[tI]; s += xv[tI]; }
    for (int m = 1; m <= 8; m <<= 1) s += __shfl_xor(s, m);
    float mu = s * (1.f / 256.f);
    float q = 0.f;
    #pragma unroll
    for (int tI = 0; tI < 16; ++tI) { xv[tI] -= mu; q += xv[tI] * xv[tI]; }
    for (int m = 1; m <= 8; m <<= 1) q += __shfl_xor(q, m);
    float rs = rsqrtf(q * (1.f / 256.f) + LN_EPS_);
    if (row < NN) {
      #pragma unroll
      for (int tI = 0; tI < 16; ++tI) {
        float o = fmaxf(xv[tI] * rs * gv[tI] + bbv[tI], 0.f);
        u16 hi = bf16_rne(o);
        u16 lo = bf16_rne(o - bf16_tof(hi));
        size_t p = (size_t)row * 256 + tI * 16 + c16;
        Uh[p] = hi; Ul[p] = lo;
      }
    }
  }
}

// ---------------- GEMM2 (20000x256 @ 256x128) 3xBF16 MFMA + bias + residual + fused LN/ReLU ----------------
__global__ __launch_bounds__(256) void gemm2_mfma(const u16* __restrict__ Ah, const u16* __restrict__ Al,
                                                  const u16* __restrict__ Bh, const u16* __restrict__ Bl,
                                                  const float* __restrict__ bias,
                                                  const float* __restrict__ gn, const float* __restrict__ bn,
                                                  float* __restrict__ h, float* __restrict__ hnb,
                                                  u16* __restrict__ hb, int first) {
  __shared__ u16 Bs[2][16384];
  int tid = threadIdx.x;
  int wv = tid >> 6, lane = tid & 63;
  int c16 = lane & 15, kg = lane >> 4;
  int row0 = blockIdx.x * 64 + wv * 16;
  int arow = row0 + c16; if (arow > NN - 1) arow = NN - 1;
  const u16* pAh = Ah + (size_t)arow * 256 + kg * 8;
  const u16* pAl = Al + (size_t)arow * 256 + kg * 8;
  f32x4 acc[8];
  #pragma unroll
  for (int tI = 0; tI < 8; ++tI) acc[tI] = (f32x4){0.f, 0.f, 0.f, 0.f};

  #pragma unroll
  for (int chunk = 0; chunk < 2; ++chunk) {
    const u16* sh = Bh + chunk * 16384;
    const u16* sl = Bl + chunk * 16384;
    #pragma unroll
    for (int it = 0; it < 8; ++it) {
      int idx = (it * 256 + tid) * 8;
      *(f32x4*)&Bs[0][idx] = *(const f32x4*)&sh[idx];
      *(f32x4*)&Bs[1][idx] = *(const f32x4*)&sl[idx];
    }
    __syncthreads();
    #pragma unroll
    for (int ks2 = 0; ks2 < 4; ++ks2) {
      int ks = chunk * 4 + ks2;
      bf16x8 ah = *(const bf16x8*)(pAh + ks * 32);
      bf16x8 al = *(const bf16x8*)(pAl + ks * 32);
      #pragma unroll
      for (int tI = 0; tI < 8; ++tI) {
        int boff = ((tI * 4 + ks2) * 64 + lane) * 8;
        bf16x8 bh = *(const bf16x8*)&Bs[0][boff];
        bf16x8 bl = *(const bf16x8*)&Bs[1][boff];
        acc[tI] = __builtin_amdgcn_mfma_f32_16x16x32_bf16(ah, bh, acc[tI], 0, 0, 0);
        acc[tI] = __builtin_amdgcn_mfma_f32_16x16x32_bf16(al, bh, acc[tI], 0, 0, 0);
        acc[tI] = __builtin_amdgcn_mfma_f32_16x16x32_bf16(ah, bl, acc[tI], 0, 0, 0);
      }
    }
    __syncthreads();
  }

  float bv[8], gv[8], bnv[8];
  #pragma unroll
  for (int tI = 0; tI < 8; ++tI) {
    int c = tI * 16 + c16;
    bv[tI] = bias[c]; gv[tI] = gn[c]; bnv[tI] = bn[c];
  }
  #pragma unroll
  for (int j = 0; j < 4; ++j) {
    int row = row0 + kg * 4 + j;
    bool ok = row < NN;
    float xv[8];
    #pragma unroll
    for (int tI = 0; tI < 8; ++tI) {
      float v = acc[tI][j] + bv[tI];
      if (!first && ok) v += h[(size_t)row * HH + tI * 16 + c16];
      xv[tI] = v;
    }
    if (ok) {
      #pragma unroll
      for (int tI = 0; tI < 8; ++tI) h[(size_t)row * HH + tI * 16 + c16] = xv[tI];
    }
    float s = 0.f;
    #pragma unroll
    for (int tI = 0; tI < 8; ++tI) s += xv[tI];
    for (int m = 1; m <= 8; m <<= 1) s += __shfl_xor(s, m);
    float mu = s * (1.f / 128.f);
    float q = 0.f;
    #pragma unroll
    for (int tI = 0; tI < 8; ++tI) { xv[tI] -= mu; q += xv[tI] * xv[tI]; }
    for (int m = 1; m <= 8; m <<= 1) q += __shfl_xor(q, m);
    float rs = rsqrtf(q * (1.f / 128.f) + LN_EPS_);
    if (ok) {
      #pragma unroll
      for (int tI = 0; tI < 8; ++tI) {
        float o = fmaxf(xv[tI] * rs * gv[tI] + bnv[tI], 0.f);
        size_t p = (size_t)row * HH + tI * 16 + c16;
        hnb[p] = o;
        hb[p] = bf16_rne(o);
      }
    }
  }
}

// ---------------- final output GEMM (Nx128 @ 128x16) ----------------
__global__ __launch_bounds__(256) void outgemm_kernel(const float* __restrict__ hn, const float* __restrict__ w,
                                                      const float* __restrict__ b, float* __restrict__ out) {
  __shared__ float Ws[HH * DOUT_];
  int tid = threadIdx.x;
  {
    const float4* s4 = (const float4*)w;
    float4* d4 = (float4*)Ws;
    d4[tid*2] = s4[tid*2]; d4[tid*2+1] = s4[tid*2+1];
  }
  __syncthreads();
  int id = blockIdx.x * 256 + tid;
  int n = id >> 4, c = id & 15;
  if (n >= NN) return;
  float s = b[c];
  const float* hr = &hn[(size_t)n*HH];
  #pragma unroll 8
  for (int k = 0; k < HH; ++k) s += hr[k] * Ws[k*DOUT_ + c];
  out[n*DOUT_ + c] = s;
}

extern "C" void kernel_launch(void* const* d_in, const int* in_sizes, int n_in,
                              void* d_out, int out_size, void* d_ws, size_t ws_size,
                              hipStream_t stream) {
  const float* x    = (const float*)d_in[0];
  const int*   ei   = (const int*)d_in[1];
  const float* eatt = (const float*)d_in[2];
  const float* enw  = (const float*)d_in[3];
  const float* enb  = (const float*)d_in[4];
  const float* eew  = (const float*)d_in[5];
  const float* eeb  = (const float*)d_in[6];
  const float* t    = (const float*)d_in[7];
  const float* m1w  = (const float*)d_in[8];
  const float* m1b  = (const float*)d_in[9];
  const float* mlg  = (const float*)d_in[10];
  const float* mlb  = (const float*)d_in[11];
  const float* m2w  = (const float*)d_in[12];
  const float* m2b  = (const float*)d_in[13];
  const float* lng  = (const float*)d_in[14];
  const float* lnb  = (const float*)d_in[15];
  const float* linw = (const float*)d_in[16];
  const float* linb = (const float*)d_in[17];
  float* out = (float*)d_out;

  char* ws = (char*)d_ws;
  size_t o = 0;
  auto take = [&](size_t bytes) { char* p = ws + o; o = (o + bytes + 255) & ~(size_t)255; return p; };
  int*    deg   = (int*)take((size_t)NN * 4);
  int*    off   = (int*)take((size_t)(NN + 1) * 4);
  int*    cur   = (int*)take((size_t)NN * 4);
  float4* edata = (float4*)take((size_t)EE * 32);
  float*  h     = (float*)take((size_t)NN * HH * 4);
  float*  hnb   = (float*)take((size_t)NN * HH * 4);
  u16*    hb    = (u16*)take((size_t)NN * HH * 2);
  u16*    tmpH  = (u16*)take((size_t)NN * HH * 2);
  u16*    tmpL  = (u16*)take((size_t)NN * HH * 2);
  u16*    Uh    = (u16*)take((size_t)NN * 256 * 2);
  u16*    Ul    = (u16*)take((size_t)NN * 256 * 2);
  u16*    w1h   = (u16*)take((size_t)LL * HH * 256 * 2);
  u16*    w1l   = (u16*)take((size_t)LL * HH * 256 * 2);
  u16*    w2h   = (u16*)take((size_t)LL * 256 * HH * 2);
  u16*    w2l   = (u16*)take((size_t)LL * 256 * HH * 2);

  const int* src = ei;
  const int* dst = ei + EE;

  hipMemsetAsync(deg, 0, (size_t)NN * 4, stream);
  hist_kernel<<<(EE + 255) / 256, 256, 0, stream>>>(dst, deg);
  scan_kernel<<<1, 1024, 0, stream>>>(deg, off, cur);
  scatter_kernel<<<(EE + 255) / 256, 256, 0, stream>>>(src, dst, (const float4*)eatt, cur, edata);
  int wblocks = (LL * HH * 256 / 8 + 255) / 256;   // 192
  wpack_kernel<<<wblocks, 256, 0, stream>>>(m1w, w1h, w1l, HH, 256, 2);
  wpack_kernel<<<wblocks, 256, 0, stream>>>(m2w, w2h, w2l, 256, HH, 4);
  encoder_kernel<<<(NN * 64 + 255) / 256, 256, 0, stream>>>(x, enw, enb, h, hb);

  int gblocks = (NN + 63) / 64;   // 313
  for (int i = 0; i < LL; ++i) {
    const float* cin = (i == 0) ? h : hnb;
    conv_kernel<<<(NN + 3) / 4, 256, 0, stream>>>(cin, hb, off, edata, eew, eeb, t, i, tmpH, tmpL);
    gemm1_mfma<<<gblocks, 256, 0, stream>>>(tmpH, tmpL,
                                            w1h + (size_t)i * 32768, w1l + (size_t)i * 32768,
                                            m1b + i * 256, mlg + i * 256, mlb + i * 256, Uh, Ul);
    int nrm = (i + 1) % LL;  // layer i's output is normed with ln params of layer i+1 (layer 0 for final norm)
    gemm2_mfma<<<gblocks, 256, 0, stream>>>(Uh, Ul,
                                            w2h + (size_t)i * 32768, w2l + (size_t)i * 32768,
                                            m2b + i * HH, lng + nrm * HH, lnb + nrm * HH,
                                            h, hnb, hb, i == 0 ? 1 : 0);
  }
  outgemm_kernel<<<(NN * DOUT_ + 255) / 256, 256, 0, stream>>>(hnb, linw, linb, out);
}

// Round 8
// 1002.844 us; speedup vs baseline: 1.1533x; 1.1533x over previous
//
#include <hip/hip_runtime.h>
#include <hip/hip_bf16.h>
#include <math.h>

#define NN 20000
#define EE 640000
#define HH 128
#define LL 12
#define DOUT_ 16
#define EPS_ 1e-7f
#define LN_EPS_ 1e-5f

typedef unsigned short u16;
typedef unsigned int u32;
typedef __attribute__((ext_vector_type(8))) short bf16x8;
typedef __attribute__((ext_vector_type(4))) float f32x4;

__device__ inline u16 bf16_rne(float v) {
  u32 u = __float_as_uint(v);
  return (u16)((u + 0x7FFFu + ((u >> 16) & 1u)) >> 16);
}
__device__ inline float bf16_tof(u16 h) { return __uint_as_float(((u32)h) << 16); }

// ---------------- CSR build ----------------
__global__ __launch_bounds__(256) void hist_kernel(const int* __restrict__ dst, int* __restrict__ deg) {
  int e = blockIdx.x * 256 + threadIdx.x;
  if (e < EE) atomicAdd(&deg[dst[e]], 1);
}

__global__ __launch_bounds__(1024) void scan_kernel(const int* __restrict__ deg, int* __restrict__ off,
                                                    int* __restrict__ cur) {
  __shared__ int part[1024];
  int tid = threadIdx.x;
  const int CH = (NN + 1023) >> 10;   // 20
  int base = tid * CH;
  int s = 0;
  for (int j = 0; j < CH; ++j) { int i = base + j; if (i < NN) s += deg[i]; }
  part[tid] = s;
  __syncthreads();
  for (int d = 1; d < 1024; d <<= 1) {
    int v = (tid >= d) ? part[tid - d] : 0;
    __syncthreads();
    part[tid] += v;
    __syncthreads();
  }
  int run = part[tid] - s;  // exclusive prefix
  for (int j = 0; j < CH; ++j) {
    int i = base + j;
    if (i < NN) { off[i] = run; cur[i] = run; run += deg[i]; }
  }
  if (tid == 1023) off[NN] = part[1023];
}

__global__ __launch_bounds__(256) void scatter_kernel(const int* __restrict__ src, const int* __restrict__ dst,
                                                      const float4* __restrict__ ea, int* __restrict__ cur,
                                                      int* __restrict__ srcs, float4* __restrict__ ea4) {
  int e = blockIdx.x * 256 + threadIdx.x;
  if (e >= EE) return;
  int d = dst[e];
  int p = atomicAdd(&cur[d], 1);
  srcs[p] = src[e];
  ea4[p] = ea[e];
}

// ---------------- weight pack: fp32 [L][K][N] -> bf16 hi/lo MFMA-fragment order ----------------
// layout: [l][chunk(2)][tI(N/16)][ks2(KSC)][lane(64)][j(8)]; k = (chunk*KSC+ks2)*32 + (lane>>4)*8 + j
__global__ __launch_bounds__(256) void wpack_kernel(const float* __restrict__ w, u16* __restrict__ dh,
                                                    u16* __restrict__ dl, int K, int N, int KSC) {
  int fid = blockIdx.x * 256 + threadIdx.x;
  int perL = (K * N) >> 3;
  if (fid >= LL * perL) return;
  int l = fid / perL, r = fid % perL;
  int lane = r & 63;
  int r2 = r >> 6;
  int ks2 = r2 % KSC; r2 /= KSC;
  int NT = N >> 4;
  int tI = r2 % NT;
  int chunk = r2 / NT;
  int c16 = lane & 15, kg = lane >> 4;
  int n = tI * 16 + c16;
  int k0 = (chunk * KSC + ks2) * 32 + kg * 8;
  const float* ws = w + (size_t)l * K * N;
  u16* oh = dh + (size_t)fid * 8;
  u16* ol = dl + (size_t)fid * 8;
  #pragma unroll
  for (int j = 0; j < 8; ++j) {
    float v = ws[(size_t)(k0 + j) * N + n];
    u16 hi = bf16_rne(v);
    oh[j] = hi;
    ol[j] = bf16_rne(v - bf16_tof(hi));
  }
}

// ---------------- encoder: h fp32 + hb bf16 plane ----------------
__global__ __launch_bounds__(256) void encoder_kernel(const float* __restrict__ x, const float* __restrict__ w,
                                                      const float* __restrict__ b, float* __restrict__ h,
                                                      u16* __restrict__ hb) {
  int id = blockIdx.x * 256 + threadIdx.x;
  if (id >= NN * 64) return;
  int n = id >> 6, cp = id & 63;
  int c0 = cp * 2;
  float x0 = x[n*3+0], x1 = x[n*3+1], x2 = x[n*3+2];
  float vx = b[c0]   + x0*w[c0]   + x1*w[HH+c0]   + x2*w[2*HH+c0];
  float vy = b[c0+1] + x0*w[c0+1] + x1*w[HH+c0+1] + x2*w[2*HH+c0+1];
  *(float2*)&h[(size_t)n*HH + c0] = make_float2(vx, vy);
  *(u32*)&hb[(size_t)n*HH + c0] = (u32)bf16_rne(vx) | ((u32)bf16_rne(vy) << 16);
}

// ---------------- GENConv aggregation: wave per dst node (round-4 proven form) ----------------
// Direct-exp softmax; UF=8 vector-load batches + scalar tail.
__global__ __launch_bounds__(256) void conv_kernel(const float* __restrict__ hn,
                                                   const u16* __restrict__ hb,
                                                   const int* __restrict__ off,
                                                   const int* __restrict__ srcs, const float4* __restrict__ ea4,
                                                   const float* __restrict__ eew, const float* __restrict__ eeb,
                                                   const float* __restrict__ t, int layer,
                                                   u16* __restrict__ tmpH, u16* __restrict__ tmpL) {
  int wid = blockIdx.x * 4 + (threadIdx.x >> 6);
  int lane = threadIdx.x & 63;
  if (wid >= NN) return;
  int c0 = lane * 2;
  float ti = t[layer];
  float w0x = eew[c0],      w0y = eew[c0+1];
  float w1x = eew[HH+c0],   w1y = eew[HH+c0+1];
  float w2x = eew[2*HH+c0], w2y = eew[2*HH+c0+1];
  float w3x = eew[3*HH+c0], w3y = eew[3*HH+c0+1];
  float bx = eeb[c0], by = eeb[c0+1];
  int e0 = off[wid], e1 = off[wid+1];
  float2 hd = *(const float2*)&hn[(size_t)wid*HH + c0];
  float den0 = 0.f, den1 = 0.f, num0 = 0.f, num1 = 0.f;

  int e = e0;
  const int UF = 8;
  for (; e + UF <= e1; e += UF) {
    int si[UF]; float4 av[UF];
    #pragma unroll
    for (int u = 0; u < UF; ++u) { si[u] = srcs[e + u]; av[u] = ea4[e + u]; }
    u32 hv[UF];
    #pragma unroll
    for (int u = 0; u < UF; ++u) hv[u] = *(const u32*)&hb[((u32)si[u] << 7) + c0];
    #pragma unroll
    for (int u = 0; u < UF; ++u) {
      float hx = bf16_tof((u16)(hv[u] & 0xffffu));
      float hy = bf16_tof((u16)(hv[u] >> 16));
      float eax = fmaf(av[u].w, w3x, fmaf(av[u].z, w2x, fmaf(av[u].y, w1x, fmaf(av[u].x, w0x, bx))));
      float eay = fmaf(av[u].w, w3y, fmaf(av[u].z, w2y, fmaf(av[u].y, w1y, fmaf(av[u].x, w0y, by))));
      float m0 = fmaxf(hx + eax, 0.f) + EPS_;
      float m1 = fmaxf(hy + eay, 0.f) + EPS_;
      float p0 = __expf(m0 * ti);
      float p1 = __expf(m1 * ti);
      den0 += p0; den1 += p1;
      num0 = fmaf(m0, p0, num0);
      num1 = fmaf(m1, p1, num1);
    }
  }
  for (; e < e1; ++e) {
    int sidx = srcs[e];
    float4 a = ea4[e];
    u32 hv = *(const u32*)&hb[((u32)sidx << 7) + c0];
    float hx = bf16_tof((u16)(hv & 0xffffu));
    float hy = bf16_tof((u16)(hv >> 16));
    float eax = fmaf(a.w, w3x, fmaf(a.z, w2x, fmaf(a.y, w1x, fmaf(a.x, w0x, bx))));
    float eay = fmaf(a.w, w3y, fmaf(a.z, w2y, fmaf(a.y, w1y, fmaf(a.x, w0y, by))));
    float m0 = fmaxf(hx + eax, 0.f) + EPS_;
    float m1 = fmaxf(hy + eay, 0.f) + EPS_;
    float p0 = __expf(m0 * ti);
    float p1 = __expf(m1 * ti);
    den0 += p0; den1 += p1;
    num0 = fmaf(m0, p0, num0);
    num1 = fmaf(m1, p1, num1);
  }
  float v0 = num0 / (den0 + 1e-16f) + hd.x;
  float v1 = num1 / (den1 + 1e-16f) + hd.y;
  u16 h0 = bf16_rne(v0), h1 = bf16_rne(v1);
  u16 l0 = bf16_rne(v0 - bf16_tof(h0)), l1 = bf16_rne(v1 - bf16_tof(h1));
  *(u32*)&tmpH[(size_t)wid*HH + c0] = (u32)h0 | ((u32)h1 << 16);
  *(u32*)&tmpL[(size_t)wid*HH + c0] = (u32)l0 | ((u32)l1 << 16);
}

// ---------------- GEMM1 (20000x128 @ 128x256) 3xBF16 MFMA, LDS-staged packed B ----------------
// epilogue: bias+LN(256)+ReLU -> plain bf16 U (unit-scale post-ReLU; lo-plane dropped)
__global__ __launch_bounds__(256) void gemm1_mfma(const u16* __restrict__ Ah, const u16* __restrict__ Al,
                                                  const u16* __restrict__ Bh, const u16* __restrict__ Bl,
                                                  const float* __restrict__ bias,
                                                  const float* __restrict__ g, const float* __restrict__ bb,
                                                  u16* __restrict__ Uh) {
  __shared__ u16 Bs[2][16384];
  int tid = threadIdx.x;
  int wv = tid >> 6, lane = tid & 63;
  int c16 = lane & 15, kg = lane >> 4;
  int row0 = blockIdx.x * 64 + wv * 16;
  int arow = row0 + c16; if (arow > NN - 1) arow = NN - 1;
  const u16* pAh = Ah + (size_t)arow * HH + kg * 8;
  const u16* pAl = Al + (size_t)arow * HH + kg * 8;
  f32x4 acc[16];
  #pragma unroll
  for (int tI = 0; tI < 16; ++tI) acc[tI] = (f32x4){0.f, 0.f, 0.f, 0.f};

  #pragma unroll
  for (int chunk = 0; chunk < 2; ++chunk) {
    const u16* sh = Bh + chunk * 16384;
    const u16* sl = Bl + chunk * 16384;
    #pragma unroll
    for (int it = 0; it < 8; ++it) {
      int idx = (it * 256 + tid) * 8;
      *(f32x4*)&Bs[0][idx] = *(const f32x4*)&sh[idx];
      *(f32x4*)&Bs[1][idx] = *(const f32x4*)&sl[idx];
    }
    __syncthreads();
    #pragma unroll
    for (int ks2 = 0; ks2 < 2; ++ks2) {
      int ks = chunk * 2 + ks2;
      bf16x8 ah = *(const bf16x8*)(pAh + ks * 32);
      bf16x8 al = *(const bf16x8*)(pAl + ks * 32);
      #pragma unroll
      for (int tI = 0; tI < 16; ++tI) {
        int boff = ((tI * 2 + ks2) * 64 + lane) * 8;
        bf16x8 bh = *(const bf16x8*)&Bs[0][boff];
        bf16x8 bl = *(const bf16x8*)&Bs[1][boff];
        acc[tI] = __builtin_amdgcn_mfma_f32_16x16x32_bf16(ah, bh, acc[tI], 0, 0, 0);
        acc[tI] = __builtin_amdgcn_mfma_f32_16x16x32_bf16(al, bh, acc[tI], 0, 0, 0);
        acc[tI] = __builtin_amdgcn_mfma_f32_16x16x32_bf16(ah, bl, acc[tI], 0, 0, 0);
      }
    }
    __syncthreads();
  }

  float bv[16], gv[16], bbv[16];
  #pragma unroll
  for (int tI = 0; tI < 16; ++tI) {
    int c = tI * 16 + c16;
    bv[tI] = bias[c]; gv[tI] = g[c]; bbv[tI] = bb[c];
  }
  #pragma unroll
  for (int j = 0; j < 4; ++j) {
    int row = row0 + kg * 4 + j;
    float xv[16], s = 0.f;
    #pragma unroll
    for (int tI = 0; tI < 16; ++tI) { xv[tI] = acc[tI][j] + bv[tI]; s += xv[tI]; }
    for (int m = 1; m <= 8; m <<= 1) s += __shfl_xor(s, m);
    float mu = s * (1.f / 256.f);
    float q = 0.f;
    #pragma unroll
    for (int tI = 0; tI < 16; ++tI) { xv[tI] -= mu; q += xv[tI] * xv[tI]; }
    for (int m = 1; m <= 8; m <<= 1) q += __shfl_xor(q, m);
    float rs = rsqrtf(q * (1.f / 256.f) + LN_EPS_);
    if (row < NN) {
      #pragma unroll
      for (int tI = 0; tI < 16; ++tI) {
        float o = fmaxf(xv[tI] * rs * gv[tI] + bbv[tI], 0.f);
        Uh[(size_t)row * 256 + tI * 16 + c16] = bf16_rne(o);
      }
    }
  }
}

// ---------------- GEMM2 (20000x256 @ 256x128) 2xBF16 MFMA (A plain bf16, W split) ----------------
// + bias + residual + fused LN/ReLU epilogue
__global__ __launch_bounds__(256) void gemm2_mfma(const u16* __restrict__ Ah,
                                                  const u16* __restrict__ Bh, const u16* __restrict__ Bl,
                                                  const float* __restrict__ bias,
                                                  const float* __restrict__ gn, const float* __restrict__ bn,
                                                  float* __restrict__ h, float* __restrict__ hnb,
                                                  u16* __restrict__ hb, int first) {
  __shared__ u16 Bs[2][16384];
  int tid = threadIdx.x;
  int wv = tid >> 6, lane = tid & 63;
  int c16 = lane & 15, kg = lane >> 4;
  int row0 = blockIdx.x * 64 + wv * 16;
  int arow = row0 + c16; if (arow > NN - 1) arow = NN - 1;
  const u16* pAh = Ah + (size_t)arow * 256 + kg * 8;
  f32x4 acc[8];
  #pragma unroll
  for (int tI = 0; tI < 8; ++tI) acc[tI] = (f32x4){0.f, 0.f, 0.f, 0.f};

  #pragma unroll
  for (int chunk = 0; chunk < 2; ++chunk) {
    const u16* sh = Bh + chunk * 16384;
    const u16* sl = Bl + chunk * 16384;
    #pragma unroll
    for (int it = 0; it < 8; ++it) {
      int idx = (it * 256 + tid) * 8;
      *(f32x4*)&Bs[0][idx] = *(const f32x4*)&sh[idx];
      *(f32x4*)&Bs[1][idx] = *(const f32x4*)&sl[idx];
    }
    __syncthreads();
    #pragma unroll
    for (int ks2 = 0; ks2 < 4; ++ks2) {
      int ks = chunk * 4 + ks2;
      bf16x8 ah = *(const bf16x8*)(pAh + ks * 32);
      #pragma unroll
      for (int tI = 0; tI < 8; ++tI) {
        int boff = ((tI * 4 + ks2) * 64 + lane) * 8;
        bf16x8 bh = *(const bf16x8*)&Bs[0][boff];
        bf16x8 bl = *(const bf16x8*)&Bs[1][boff];
        acc[tI] = __builtin_amdgcn_mfma_f32_16x16x32_bf16(ah, bh, acc[tI], 0, 0, 0);
        acc[tI] = __builtin_amdgcn_mfma_f32_16x16x32_bf16(ah, bl, acc[tI], 0, 0, 0);
      }
    }
    __syncthreads();
  }

  float bv[8], gv[8], bnv[8];
  #pragma unroll
  for (int tI = 0; tI < 8; ++tI) {
    int c = tI * 16 + c16;
    bv[tI] = bias[c]; gv[tI] = gn[c]; bnv[tI] = bn[c];
  }
  #pragma unroll
  for (int j = 0; j < 4; ++j) {
    int row = row0 + kg * 4 + j;
    bool ok = row < NN;
    float xv[8];
    #pragma unroll
    for (int tI = 0; tI < 8; ++tI) {
      float v = acc[tI][j] + bv[tI];
      if (!first && ok) v += h[(size_t)row * HH + tI * 16 + c16];
      xv[tI] = v;
    }
    if (ok) {
      #pragma unroll
      for (int tI = 0; tI < 8; ++tI) h[(size_t)row * HH + tI * 16 + c16] = xv[tI];
    }
    float s = 0.f;
    #pragma unroll
    for (int tI = 0; tI < 8; ++tI) s += xv[tI];
    for (int m = 1; m <= 8; m <<= 1) s += __shfl_xor(s, m);
    float mu = s * (1.f / 128.f);
    float q = 0.f;
    #pragma unroll
    for (int tI = 0; tI < 8; ++tI) { xv[tI] -= mu; q += xv[tI] * xv[tI]; }
    for (int m = 1; m <= 8; m <<= 1) q += __shfl_xor(q, m);
    float rs = rsqrtf(q * (1.f / 128.f) + LN_EPS_);
    if (ok) {
      #pragma unroll
      for (int tI = 0; tI < 8; ++tI) {
        float o = fmaxf(xv[tI] * rs * gv[tI] + bnv[tI], 0.f);
        size_t p = (size_t)row * HH + tI * 16 + c16;
        hnb[p] = o;
        hb[p] = bf16_rne(o);
      }
    }
  }
}

// ---------------- final output GEMM (Nx128 @ 128x16) ----------------
__global__ __launch_bounds__(256) void outgemm_kernel(const float* __restrict__ hn, const float* __restrict__ w,
                                                      const float* __restrict__ b, float* __restrict__ out) {
  __shared__ float Ws[HH * DOUT_];
  int tid = threadIdx.x;
  {
    const float4* s4 = (const float4*)w;
    float4* d4 = (float4*)Ws;
    d4[tid*2] = s4[tid*2]; d4[tid*2+1] = s4[tid*2+1];
  }
  __syncthreads();
  int id = blockIdx.x * 256 + tid;
  int n = id >> 4, c = id & 15;
  if (n >= NN) return;
  float s = b[c];
  const float* hr = &hn[(size_t)n*HH];
  #pragma unroll 8
  for (int k = 0; k < HH; ++k) s += hr[k] * Ws[k*DOUT_ + c];
  out[n*DOUT_ + c] = s;
}

extern "C" void kernel_launch(void* const* d_in, const int* in_sizes, int n_in,
                              void* d_out, int out_size, void* d_ws, size_t ws_size,
                              hipStream_t stream) {
  const float* x    = (const float*)d_in[0];
  const int*   ei   = (const int*)d_in[1];
  const float* eatt = (const float*)d_in[2];
  const float* enw  = (const float*)d_in[3];
  const float* enb  = (const float*)d_in[4];
  const float* eew  = (const float*)d_in[5];
  const float* eeb  = (const float*)d_in[6];
  const float* t    = (const float*)d_in[7];
  const float* m1w  = (const float*)d_in[8];
  const float* m1b  = (const float*)d_in[9];
  const float* mlg  = (const float*)d_in[10];
  const float* mlb  = (const float*)d_in[11];
  const float* m2w  = (const float*)d_in[12];
  const float* m2b  = (const float*)d_in[13];
  const float* lng  = (const float*)d_in[14];
  const float* lnb  = (const float*)d_in[15];
  const float* linw = (const float*)d_in[16];
  const float* linb = (const float*)d_in[17];
  float* out = (float*)d_out;

  char* ws = (char*)d_ws;
  size_t o = 0;
  auto take = [&](size_t bytes) { char* p = ws + o; o = (o + bytes + 255) & ~(size_t)255; return p; };
  int*    deg  = (int*)take((size_t)NN * 4);
  int*    off  = (int*)take((size_t)(NN + 1) * 4);
  int*    cur  = (int*)take((size_t)NN * 4);
  int*    srcs = (int*)take((size_t)EE * 4);
  float4* ea4  = (float4*)take((size_t)EE * 16);
  float*  h    = (float*)take((size_t)NN * HH * 4);
  float*  hnb  = (float*)take((size_t)NN * HH * 4);
  u16*    hb   = (u16*)take((size_t)NN * HH * 2);
  u16*    tmpH = (u16*)take((size_t)NN * HH * 2);
  u16*    tmpL = (u16*)take((size_t)NN * HH * 2);
  u16*    Uh   = (u16*)take((size_t)NN * 256 * 2);
  u16*    w1h  = (u16*)take((size_t)LL * HH * 256 * 2);
  u16*    w1l  = (u16*)take((size_t)LL * HH * 256 * 2);
  u16*    w2h  = (u16*)take((size_t)LL * 256 * HH * 2);
  u16*    w2l  = (u16*)take((size_t)LL * 256 * HH * 2);

  const int* src = ei;
  const int* dst = ei + EE;

  hipMemsetAsync(deg, 0, (size_t)NN * 4, stream);
  hist_kernel<<<(EE + 255) / 256, 256, 0, stream>>>(dst, deg);
  scan_kernel<<<1, 1024, 0, stream>>>(deg, off, cur);
  scatter_kernel<<<(EE + 255) / 256, 256, 0, stream>>>(src, dst, (const float4*)eatt, cur, srcs, ea4);
  int wblocks = (LL * HH * 256 / 8 + 255) / 256;   // 192
  wpack_kernel<<<wblocks, 256, 0, stream>>>(m1w, w1h, w1l, HH, 256, 2);
  wpack_kernel<<<wblocks, 256, 0, stream>>>(m2w, w2h, w2l, 256, HH, 4);
  encoder_kernel<<<(NN * 64 + 255) / 256, 256, 0, stream>>>(x, enw, enb, h, hb);

  int gblocks = (NN + 63) / 64;   // 313
  for (int i = 0; i < LL; ++i) {
    const float* cin = (i == 0) ? h : hnb;
    conv_kernel<<<(NN + 3) / 4, 256, 0, stream>>>(cin, hb, off, srcs, ea4, eew, eeb, t, i, tmpH, tmpL);
    gemm1_mfma<<<gblocks, 256, 0, stream>>>(tmpH, tmpL,
                                            w1h + (size_t)i * 32768, w1l + (size_t)i * 32768,
                                            m1b + i * 256, mlg + i * 256, mlb + i * 256, Uh);
    int nrm = (i + 1) % LL;  // layer i's output is normed with ln params of layer i+1 (layer 0 for final norm)
    gemm2_mfma<<<gblocks, 256, 0, stream>>>(Uh,
                                            w2h + (size_t)i * 32768, w2l + (size_t)i * 32768,
                                            m2b + i * HH, lng + nrm * HH, lnb + nrm * HH,
                                            h, hnb, hb, i == 0 ? 1 : 0);
  }
  outgemm_kernel<<<(NN * DOUT_ + 255) / 256, 256, 0, stream>>>(hnb, linw, linb, out);
}